// Round 5
// baseline (755.153 us; speedup 1.0000x reference)
//
#include <hip/hip_runtime.h>
#include <math.h>

#define B_   64
#define T_   500
#define IN_  1024
#define G_   8
#define HG_  128
#define J3_  384   // 3*HG

typedef _Float16 half8 __attribute__((ext_vector_type(8)));
typedef _Float16 half4 __attribute__((ext_vector_type(4)));
typedef float    f32x4 __attribute__((ext_vector_type(4)));

static __device__ __forceinline__ half8 cvt_half8(const float* p) {
    const float4 a = *(const float4*)p;
    const float4 b = *(const float4*)(p + 4);
    half8 h;
    h[0] = (_Float16)a.x; h[1] = (_Float16)a.y; h[2] = (_Float16)a.z; h[3] = (_Float16)a.w;
    h[4] = (_Float16)b.x; h[5] = (_Float16)b.y; h[6] = (_Float16)b.z; h[7] = (_Float16)b.w;
    return h;
}

// Make a fragment opaque to the compiler so it CANNOT be rematerialized from
// its defining global load (round-2/round-4 disease: allocator re-loads W
// inside the recurrence loop). Empty asm, reg-to-reg, zero cost.
static __device__ __forceinline__ void pin_frag(half8& h) {
    f32x4 t = __builtin_bit_cast(f32x4, h);
    float a = t[0], b = t[1], c = t[2], d = t[3];
    asm volatile("" : "+v"(a), "+v"(b), "+v"(c), "+v"(d));
    t[0] = a; t[1] = b; t[2] = c; t[3] = d;
    h = __builtin_bit_cast(half8, t);
}

// ---------------------------------------------------------------------------
// Kernel A (MFMA) — unchanged from round 4 (~168 us).
// ---------------------------------------------------------------------------
__global__ __launch_bounds__(256, 2)
void gru_xproj(const float* __restrict__ x, const float* __restrict__ Wih,
               const float* __restrict__ bih, _Float16* __restrict__ xp,
               int t0)
{
    __shared__ _Float16 cs[128 * 128];

    const int lin = blockIdx.x;
    const int g   = lin & 7;
    const int rem = lin >> 3;
    const int jb  = rem % 3;
    const int q   = rem / 3;
    const int j0  = jb * 128;
    const int row0 = q * 128;

    const int tid  = threadIdx.x;
    const int lane = tid & 63;
    const int w    = tid >> 6;
    const int wm   = w >> 1, wn = w & 1;
    const int lr   = lane & 15, hi = lane >> 4;

    const float* xbase[4];
#pragma unroll
    for (int mi = 0; mi < 4; ++mi) {
        const int row = row0 + wm * 64 + mi * 16 + lr;
        const int b   = row & 63;
        const int tau = row >> 6;
        xbase[mi] = x + ((size_t)b * T_ + t0 + tau) * IN_ + g * HG_;
    }
    const float* wbase[4];
#pragma unroll
    for (int ni = 0; ni < 4; ++ni)
        wbase[ni] = Wih + (size_t)(g * J3_ + j0 + wn * 64 + ni * 16 + lr) * HG_;

    f32x4 acc[4][4];
#pragma unroll
    for (int mi = 0; mi < 4; ++mi)
#pragma unroll
        for (int ni = 0; ni < 4; ++ni) acc[mi][ni] = (f32x4){0.f, 0.f, 0.f, 0.f};

#pragma unroll
    for (int kt = 0; kt < 4; ++kt) {
        half8 af[4], bf[4];
#pragma unroll
        for (int mi = 0; mi < 4; ++mi) af[mi] = cvt_half8(xbase[mi] + kt * 32 + hi * 8);
#pragma unroll
        for (int ni = 0; ni < 4; ++ni) bf[ni] = cvt_half8(wbase[ni] + kt * 32 + hi * 8);
#pragma unroll
        for (int mi = 0; mi < 4; ++mi)
#pragma unroll
            for (int ni = 0; ni < 4; ++ni)
                acc[mi][ni] = __builtin_amdgcn_mfma_f32_16x16x32_f16(af[mi], bf[ni], acc[mi][ni], 0, 0, 0);
    }

    float bias[4];
#pragma unroll
    for (int ni = 0; ni < 4; ++ni) bias[ni] = bih[g * J3_ + j0 + wn * 64 + ni * 16 + lr];

#pragma unroll
    for (int mi = 0; mi < 4; ++mi)
#pragma unroll
        for (int ni = 0; ni < 4; ++ni)
#pragma unroll
            for (int r = 0; r < 4; ++r) {
                const int row  = wm * 64 + mi * 16 + hi * 4 + r;
                const int colb = (wn * 64 + ni * 16 + lr) * 2;
                const int addr = row * 256 + (colb ^ ((row & 7) << 4));
                *(_Float16*)((char*)cs + addr) = (_Float16)(acc[mi][ni][r] + bias[ni]);
            }
    __syncthreads();

#pragma unroll
    for (int s = 0; s < 8; ++s) {
        const int u   = s * 256 + tid;
        const int row = u >> 4;
        const int c16 = u & 15;
        const int addr = row * 256 + ((c16 * 16) ^ ((row & 7) << 4));
        const half8 v = *(const half8*)((const char*)cs + addr);
        *(half8*)(xp + ((size_t)(row0 + row) * G_ + g) * J3_ + j0 + c16 * 8) = v;
    }
}

// ---------------------------------------------------------------------------
// Kernel B (structure F): latency-optimized recurrence.
// 256 blocks (b-pair x g), 512 thr = 8 waves, 2 sequences via B-col parity.
// Wave w owns j in [16w,16w+16) for ALL THREE gates (A rows p*128+16w+lr),
// so D-frags give each lane hr/hz/hn for its own 4 j's -> gates are lane-
// local (no hp LDS bounce, no second barrier). h double-buffered in LDS
// (1 KB) -> exactly ONE barrier per step. W_hh frags asm-pinned in VGPRs.
// ---------------------------------------------------------------------------
__global__ __launch_bounds__(512, 2)
void gru_rec(const float* __restrict__ Whh, const float* __restrict__ bhh,
             const _Float16* __restrict__ xp, float* __restrict__ out,
             float* __restrict__ hstate, int t0, int tc)
{
    const int tid  = threadIdx.x;
    const int lane = tid & 63;
    const int w    = tid >> 6;          // wave 0..7
    const int lr   = lane & 15;
    const int hi   = lane >> 4;
    const int blk  = blockIdx.x;        // 0..255
    const int g    = blk & 7;           // == XCD
    const int bp   = blk >> 3;

    __shared__ _Float16 h16[2][2][HG_]; // [buf][seq][j], 1 KB

    const int jl = w * 16 + hi * 4;     // this lane's j base (4 consecutive)
    const int sq = lr & 1;              // sequence parity (valid on ALL lanes)
    const int b  = bp * 2 + sq;

    // persistent A-frags: gate p, rows p*128 + w*16 + lr, pinned in VGPRs
    half8 af[3][4];
#pragma unroll
    for (int p = 0; p < 3; ++p)
#pragma unroll
        for (int kt = 0; kt < 4; ++kt) {
            af[p][kt] = cvt_half8(Whh + (size_t)(g * J3_ + p * 128 + w * 16 + lr) * HG_
                                      + kt * 32 + hi * 8);
            pin_frag(af[p][kt]);
        }

    // biases for this lane's 4 j's (all lanes)
    const f32x4 br = *(const f32x4*)(bhh + g * J3_ +       jl);
    const f32x4 bz = *(const f32x4*)(bhh + g * J3_ + 128 + jl);
    const f32x4 bn = *(const f32x4*)(bhh + g * J3_ + 256 + jl);

    // initial h (fp32 persistent per lane)
    f32x4 hreg;
    if (t0 == 0) hreg = (f32x4){0.f, 0.f, 0.f, 0.f};
    else         hreg = *(const f32x4*)(hstate + ((size_t)b * G_ + g) * HG_ + jl);
    if (lr < 2) {
        half4 h0;
#pragma unroll
        for (int r = 0; r < 4; ++r) h0[r] = (_Float16)hreg[r];
        *(half4*)(&h16[0][lr][jl]) = h0;
    }
    __syncthreads();

    const size_t TS = (size_t)64 * G_ * J3_;
    const _Float16* xpbg = xp + ((size_t)b * G_ + g) * J3_;
    float* outbg = out + (size_t)b * T_ * IN_ + (size_t)t0 * IN_ + g * HG_;

    // xp for tau=0
    half4 xr4 = *(const half4*)(xpbg + jl);
    half4 xz4 = *(const half4*)(xpbg + 128 + jl);
    half4 xn4 = *(const half4*)(xpbg + 256 + jl);

    for (int tau = 0; tau < tc; ++tau) {
        // prefetch next step's xp (consumed after next barrier)
        const int tn = (tau + 1 < tc) ? tau + 1 : tau;
        const _Float16* qn = xpbg + (size_t)tn * TS;
        half4 nxr = *(const half4*)(qn + jl);
        half4 nxz = *(const half4*)(qn + 128 + jl);
        half4 nxn = *(const half4*)(qn + 256 + jl);

        const int pb = tau & 1;

        // B-frags: h of this lane's sequence, broadcast from LDS
        half8 bf[4];
#pragma unroll
        for (int kt = 0; kt < 4; ++kt)
            bf[kt] = *(const half8*)(&h16[pb][sq][kt * 32 + hi * 8]);

        // 12 MFMA: gate p -> acc[p]; K accumulated in-chain
        f32x4 acc[3];
#pragma unroll
        for (int p = 0; p < 3; ++p) {
            f32x4 a = (f32x4){0.f, 0.f, 0.f, 0.f};
#pragma unroll
            for (int kt = 0; kt < 4; ++kt)
                a = __builtin_amdgcn_mfma_f32_16x16x32_f16(af[p][kt], bf[kt], a, 0, 0, 0);
            acc[p] = a;
        }

        // gates: fully lane-local, all 64 lanes (8x duplicated, no divergence)
        f32x4 hnew;
#pragma unroll
        for (int r = 0; r < 4; ++r) {
            const float hr = acc[0][r] + br[r];
            const float hz = acc[1][r] + bz[r];
            const float hn = acc[2][r] + bn[r];
            const float xr = (float)xr4[r];
            const float xz = (float)xz4[r];
            const float xn = (float)xn4[r];
            const float rg = 1.f / (1.f + __expf(-(xr + hr)));
            const float z  = 1.f / (1.f + __expf(-(xz + hz)));
            const float pre = xn + rg * hn;
            const float e2  = __expf(-2.f * fabsf(pre));
            float th = (1.f - e2) / (1.f + e2);
            th = copysignf(th, pre);
            hnew[r] = (1.f - z) * th + z * hreg[r];
        }
        hreg = hnew;

        if (lr < 2) {
            half4 hh;
#pragma unroll
            for (int r = 0; r < 4; ++r) hh[r] = (_Float16)hnew[r];
            *(half4*)(&h16[pb ^ 1][lr][jl]) = hh;           // next step's h
            *(f32x4*)(outbg + (size_t)tau * IN_ + jl) = hnew;
        }
        __syncthreads();   // the ONLY barrier per step

        xr4 = nxr; xz4 = nxz; xn4 = nxn;
    }

    if (lr < 2) *(f32x4*)(hstate + ((size_t)b * G_ + g) * HG_ + jl) = hreg;
}

// ---------------------------------------------------------------------------
extern "C" void kernel_launch(void* const* d_in, const int* in_sizes, int n_in,
                              void* d_out, int out_size, void* d_ws, size_t ws_size,
                              hipStream_t stream) {
    (void)in_sizes; (void)n_in; (void)out_size;
    const float* x   = (const float*)d_in[0];
    const float* Wih = (const float*)d_in[1];
    const float* Whh = (const float*)d_in[2];
    const float* bih = (const float*)d_in[3];
    const float* bhh = (const float*)d_in[4];
    float* out = (float*)d_out;

    const size_t hBytes = (size_t)B_ * G_ * HG_ * sizeof(float);
    float*     hstate = (float*)d_ws;
    _Float16*  xpbuf  = (_Float16*)((char*)d_ws + hBytes);

    const size_t perT  = (size_t)B_ * G_ * J3_ * sizeof(_Float16);
    const size_t avail = (ws_size > hBytes) ? (ws_size - hBytes) : 0;

    const int cands[8] = {500, 250, 100, 50, 20, 10, 4, 2};
    int tc = 2;
    for (int i = 0; i < 8; ++i) {
        if ((size_t)cands[i] * perT <= avail) { tc = cands[i]; break; }
    }

    for (int t0 = 0; t0 < T_; t0 += tc) {
        const int RB = tc * 64 / 128;
        gru_xproj<<<24 * RB, 256, 0, stream>>>(x, Wih, bih, xpbuf, t0);
        gru_rec<<<256, 512, 0, stream>>>(Whh, bhh, xpbuf, out, hstate, t0, tc);
    }
}

// Round 6
// 665.061 us; speedup vs baseline: 1.1355x; 1.1355x over previous
//
#include <hip/hip_runtime.h>
#include <math.h>

#define B_   64
#define T_   500
#define IN_  1024
#define G_   8
#define HG_  128
#define J3_  384   // 3*HG

typedef _Float16 half8 __attribute__((ext_vector_type(8)));
typedef _Float16 half4 __attribute__((ext_vector_type(4)));
typedef float    f32x4 __attribute__((ext_vector_type(4)));

static __device__ __forceinline__ half8 cvt_half8(const float* p) {
    const float4 a = *(const float4*)p;
    const float4 b = *(const float4*)(p + 4);
    half8 h;
    h[0] = (_Float16)a.x; h[1] = (_Float16)a.y; h[2] = (_Float16)a.z; h[3] = (_Float16)a.w;
    h[4] = (_Float16)b.x; h[5] = (_Float16)b.y; h[6] = (_Float16)b.z; h[7] = (_Float16)b.w;
    return h;
}

// opaque reg-to-reg barrier: prevents rematerialization of W fragments
static __device__ __forceinline__ void pin_frag(half8& h) {
    f32x4 t = __builtin_bit_cast(f32x4, h);
    float a = t[0], b = t[1], c = t[2], d = t[3];
    asm volatile("" : "+v"(a), "+v"(b), "+v"(c), "+v"(d));
    t[0] = a; t[1] = b; t[2] = c; t[3] = d;
    h = __builtin_bit_cast(half8, t);
}

// ---------------------------------------------------------------------------
// Kernel 0: cast x (fp32) -> x16 (f16), one-shot, memory-bound.
// ---------------------------------------------------------------------------
__global__ __launch_bounds__(256)
void cvt_x(const float* __restrict__ x, _Float16* __restrict__ x16)
{
    const size_t n4 = (size_t)B_ * T_ * IN_ / 4;        // 8,192,000
    const size_t stride = (size_t)gridDim.x * 256;
    for (size_t i = (size_t)blockIdx.x * 256 + threadIdx.x; i < n4; i += stride) {
        const float4 v = ((const float4*)x)[i];
        half4 h;
        h[0] = (_Float16)v.x; h[1] = (_Float16)v.y;
        h[2] = (_Float16)v.z; h[3] = (_Float16)v.w;
        ((half4*)x16)[i] = h;
    }
}

// ---------------------------------------------------------------------------
// Kernel 1 (structure G): fully fused GRU. 32 blocks x 512 thr.
// Block: (g = blk&7, bq = blk>>3). 16 sequences per block: seq col = lr,
// b = bq*16 + lr. Wave w owns j in [16w, 16w+16) for all 3 gates.
// Per step: 12 MFMA x-proj (A=W_ih frags, B=x16 prefetched 2 steps ahead)
//         + 12 MFMA h-proj (A=W_hh frags, B=h16 from swizzled LDS)
//         + lane-local gates (zero duplication) + swizzled h16 write
//         + coalesced out store + ONE barrier.
// W frags: 24 x half8 = 96 VGPR, asm-pinned.
// ---------------------------------------------------------------------------
__global__ __launch_bounds__(512, 2)
void gru_fused(const float* __restrict__ Wih, const float* __restrict__ Whh,
               const float* __restrict__ bih, const float* __restrict__ bhh,
               const _Float16* __restrict__ x16, float* __restrict__ out)
{
    const int tid  = threadIdx.x;
    const int lane = tid & 63;
    const int w    = tid >> 6;        // wave 0..7 == j-tile
    const int lr   = lane & 15;       // seq within block / MFMA col
    const int hi   = lane >> 4;       // 0..3
    const int blk  = blockIdx.x;      // 0..31
    const int g    = blk & 7;
    const int bq   = blk >> 3;        // 0..3
    const int b    = bq * 16 + lr;    // this lane's sequence
    const int jl   = w * 16 + hi * 4; // this lane's j base (4 consecutive)

    __shared__ _Float16 hmem[2][16 * 128];   // [buf][swizzled seq-major], 8 KB

    // ---- persistent pinned fragments: rows p*128 + 16w + lr, k = kt*32+hi*8 ----
    half8 aI[3][4], aH[3][4];
#pragma unroll
    for (int p = 0; p < 3; ++p)
#pragma unroll
        for (int kt = 0; kt < 4; ++kt) {
            const size_t roff = (size_t)(g * J3_ + p * 128 + w * 16 + lr) * HG_
                              + kt * 32 + hi * 8;
            aI[p][kt] = cvt_half8(Wih + roff);  pin_frag(aI[p][kt]);
            aH[p][kt] = cvt_half8(Whh + roff);  pin_frag(aH[p][kt]);
        }

    // ---- biases for this lane's 4 j's; fold b_ih+b_hh for r,z gates ----
    const float* bi = bih + g * J3_;
    const float* bh = bhh + g * J3_;
    f32x4 brz0, brz1, bin_, bhn_;
    {
        const f32x4 i0 = *(const f32x4*)(bi + jl);
        const f32x4 h0 = *(const f32x4*)(bh + jl);
        const f32x4 i1 = *(const f32x4*)(bi + 128 + jl);
        const f32x4 h1 = *(const f32x4*)(bh + 128 + jl);
        brz0 = i0 + h0; brz1 = i1 + h1;
        bin_ = *(const f32x4*)(bi + 256 + jl);
        bhn_ = *(const f32x4*)(bh + 256 + jl);
    }

    // ---- h = 0 init (each lane writes its own swizzled slot in buf 0) ----
    f32x4 hreg = (f32x4){0.f, 0.f, 0.f, 0.f};
    {
        const int gi = (2 * w + (hi >> 1)) ^ (lr & 7);
        half4 z4 = (half4){(_Float16)0.f, (_Float16)0.f, (_Float16)0.f, (_Float16)0.f};
        *(half4*)&hmem[0][lr * 128 + gi * 8 + (hi & 1) * 4] = z4;
    }
    __syncthreads();

    const _Float16* xrow = x16 + (size_t)b * T_ * IN_ + g * HG_;   // + tau*IN_
    float*          orow = out + (size_t)b * T_ * IN_ + g * HG_;   // + tau*IN_

    // ---- prologue: prefetch x frags for tau = 0, 1 ----
    half8 bxA[4], bxB[4];
#pragma unroll
    for (int kt = 0; kt < 4; ++kt) bxA[kt] = *(const half8*)(xrow + kt * 32 + hi * 8);
#pragma unroll
    for (int kt = 0; kt < 4; ++kt) bxB[kt] = *(const half8*)(xrow + IN_ + kt * 32 + hi * 8);

#define GRU_STEP(TAU, BX)                                                          \
    do {                                                                           \
        /* x-projection (h-independent; BX arrived >=1 step ago) */                \
        f32x4 xa0 = (f32x4){0.f,0.f,0.f,0.f}, xa1 = xa0, xa2 = xa0;                \
        _Pragma("unroll")                                                          \
        for (int kt = 0; kt < 4; ++kt) {                                           \
            xa0 = __builtin_amdgcn_mfma_f32_16x16x32_f16(aI[0][kt], BX[kt], xa0, 0, 0, 0); \
            xa1 = __builtin_amdgcn_mfma_f32_16x16x32_f16(aI[1][kt], BX[kt], xa1, 0, 0, 0); \
            xa2 = __builtin_amdgcn_mfma_f32_16x16x32_f16(aI[2][kt], BX[kt], xa2, 0, 0, 0); \
        }                                                                          \
        /* reload BX for TAU+2 (2 full steps of latency budget) */                 \
        {                                                                          \
            int tn = (TAU) + 2; if (tn > T_ - 1) tn = T_ - 1;                      \
            const _Float16* px = xrow + (size_t)tn * IN_;                          \
            _Pragma("unroll")                                                      \
            for (int kt = 0; kt < 4; ++kt)                                         \
                BX[kt] = *(const half8*)(px + kt * 32 + hi * 8);                   \
        }                                                                          \
        /* h-projection from swizzled LDS */                                       \
        const int pb = (TAU) & 1;                                                  \
        f32x4 ha0 = (f32x4){0.f,0.f,0.f,0.f}, ha1 = ha0, ha2 = ha0;                \
        _Pragma("unroll")                                                          \
        for (int kt = 0; kt < 4; ++kt) {                                           \
            const half8 bf = *(const half8*)&hmem[pb][lr * 128 + ((4 * kt + hi) ^ (lr & 7)) * 8]; \
            ha0 = __builtin_amdgcn_mfma_f32_16x16x32_f16(aH[0][kt], bf, ha0, 0, 0, 0); \
            ha1 = __builtin_amdgcn_mfma_f32_16x16x32_f16(aH[1][kt], bf, ha1, 0, 0, 0); \
            ha2 = __builtin_amdgcn_mfma_f32_16x16x32_f16(aH[2][kt], bf, ha2, 0, 0, 0); \
        }                                                                          \
        /* lane-local gates (seq = lr, 4 j's), all fp32 */                         \
        f32x4 hnew;                                                                \
        _Pragma("unroll")                                                          \
        for (int r = 0; r < 4; ++r) {                                              \
            const float ar  = xa0[r] + ha0[r] + brz0[r];                           \
            const float az  = xa1[r] + ha1[r] + brz1[r];                           \
            const float xnv = xa2[r] + bin_[r];                                    \
            const float hnv = ha2[r] + bhn_[r];                                    \
            const float rg = __builtin_amdgcn_rcpf(1.f + __builtin_amdgcn_exp2f(-1.4426950f * ar)); \
            const float zg = __builtin_amdgcn_rcpf(1.f + __builtin_amdgcn_exp2f(-1.4426950f * az)); \
            const float pre = xnv + rg * hnv;                                      \
            const float th  = 2.f * __builtin_amdgcn_rcpf(1.f + __builtin_amdgcn_exp2f(-2.8853900f * pre)) - 1.f; \
            hnew[r] = th + zg * (hreg[r] - th);                                    \
        }                                                                          \
        hreg = hnew;                                                               \
        /* write h for next step (swizzled) + output store */                      \
        {                                                                          \
            half4 hh;                                                              \
            _Pragma("unroll")                                                      \
            for (int r = 0; r < 4; ++r) hh[r] = (_Float16)hnew[r];                 \
            const int gi = (2 * w + (hi >> 1)) ^ (lr & 7);                         \
            *(half4*)&hmem[pb ^ 1][lr * 128 + gi * 8 + (hi & 1) * 4] = hh;         \
            *(f32x4*)(orow + (size_t)(TAU) * IN_ + jl) = hnew;                     \
        }                                                                          \
        __syncthreads();                                                           \
    } while (0)

    for (int t = 0; t < T_; t += 2) {
        GRU_STEP(t,     bxA);
        GRU_STEP(t + 1, bxB);
    }
#undef GRU_STEP
}

// ---------------------------------------------------------------------------
extern "C" void kernel_launch(void* const* d_in, const int* in_sizes, int n_in,
                              void* d_out, int out_size, void* d_ws, size_t ws_size,
                              hipStream_t stream) {
    (void)in_sizes; (void)n_in; (void)out_size; (void)ws_size;
    const float* x   = (const float*)d_in[0];
    const float* Wih = (const float*)d_in[1];
    const float* Whh = (const float*)d_in[2];
    const float* bih = (const float*)d_in[3];
    const float* bhh = (const float*)d_in[4];
    float* out = (float*)d_out;

    _Float16* x16 = (_Float16*)d_ws;    // 64*500*1024*2 = 65.5 MB (ws held ~197MB before)

    cvt_x<<<4096, 256, 0, stream>>>(x, x16);
    gru_fused<<<32, 512, 0, stream>>>(Wih, Whh, bih, bhh, x16, out);
}

// Round 7
// 556.907 us; speedup vs baseline: 1.3560x; 1.1942x over previous
//
#include <hip/hip_runtime.h>
#include <math.h>

#define B_   64
#define T_   500
#define IN_  1024
#define G_   8
#define HG_  128
#define J3_  384   // 3*HG

typedef _Float16 half8 __attribute__((ext_vector_type(8)));
typedef _Float16 half4 __attribute__((ext_vector_type(4)));
typedef float    f32x4 __attribute__((ext_vector_type(4)));

static __device__ __forceinline__ half8 cvt_half8(const float* p) {
    const float4 a = *(const float4*)p;
    const float4 b = *(const float4*)(p + 4);
    half8 h;
    h[0] = (_Float16)a.x; h[1] = (_Float16)a.y; h[2] = (_Float16)a.z; h[3] = (_Float16)a.w;
    h[4] = (_Float16)b.x; h[5] = (_Float16)b.y; h[6] = (_Float16)b.z; h[7] = (_Float16)b.w;
    return h;
}

// opaque reg-to-reg barrier: prevents rematerialization of W fragments
static __device__ __forceinline__ void pin_frag(half8& h) {
    f32x4 t = __builtin_bit_cast(f32x4, h);
    float a = t[0], b = t[1], c = t[2], d = t[3];
    asm volatile("" : "+v"(a), "+v"(b), "+v"(c), "+v"(d));
    t[0] = a; t[1] = b; t[2] = c; t[3] = d;
    h = __builtin_bit_cast(half8, t);
}

// LDS-only barrier: orders ds ops across the workgroup WITHOUT draining vmcnt.
// __syncthreads() would emit s_waitcnt vmcnt(0) lgkmcnt(0) before s_barrier,
// forcing every step to wait for its prefetch loads + out stores (the round-6
// 3120cy/step stall). Global loads here are read-only and stores are never
// read back, so LDS ordering alone is sufficient for the h16 exchange.
static __device__ __forceinline__ void barrier_lds_only() {
    asm volatile("s_waitcnt lgkmcnt(0)\n\ts_barrier" ::: "memory");
}

// ---------------------------------------------------------------------------
// Kernel 0: cast x (fp32) -> x16 (f16), one-shot, memory-bound (~15 us).
// ---------------------------------------------------------------------------
__global__ __launch_bounds__(256)
void cvt_x(const float* __restrict__ x, _Float16* __restrict__ x16)
{
    const size_t n4 = (size_t)B_ * T_ * IN_ / 4;        // 8,192,000
    const size_t stride = (size_t)gridDim.x * 256;
    for (size_t i = (size_t)blockIdx.x * 256 + threadIdx.x; i < n4; i += stride) {
        const float4 v = ((const float4*)x)[i];
        half4 h;
        h[0] = (_Float16)v.x; h[1] = (_Float16)v.y;
        h[2] = (_Float16)v.z; h[3] = (_Float16)v.w;
        ((half4*)x16)[i] = h;
    }
}

// ---------------------------------------------------------------------------
// Kernel 1 (structure G + non-draining barrier): fully fused GRU.
// 32 blocks x 512 thr; 16 sequences per block (MFMA col = seq = lr).
// Wave w owns j in [16w, 16w+16) for all 3 gates; gates fully lane-local.
// Per step: 12 MFMA x-proj (B=x16, prefetched 2 steps ahead, loads stay in
// flight across barriers) + 12 MFMA h-proj (B=h16 from swizzled LDS)
// + lane-local gates + swizzled h16 write + out store + ONE lds-only barrier.
// ---------------------------------------------------------------------------
__global__ __launch_bounds__(512, 2)
void gru_fused(const float* __restrict__ Wih, const float* __restrict__ Whh,
               const float* __restrict__ bih, const float* __restrict__ bhh,
               const _Float16* __restrict__ x16, float* __restrict__ out)
{
    const int tid  = threadIdx.x;
    const int lane = tid & 63;
    const int w    = tid >> 6;        // wave 0..7 == j-tile
    const int lr   = lane & 15;       // seq within block / MFMA col
    const int hi   = lane >> 4;       // 0..3
    const int blk  = blockIdx.x;      // 0..31
    const int g    = blk & 7;
    const int bq   = blk >> 3;        // 0..3
    const int b    = bq * 16 + lr;    // this lane's sequence
    const int jl   = w * 16 + hi * 4; // this lane's j base (4 consecutive)

    __shared__ _Float16 hmem[2][16 * 128];   // [buf][swizzled seq-major], 8 KB

    // ---- persistent pinned fragments: rows p*128 + 16w + lr, k = kt*32+hi*8 ----
    half8 aI[3][4], aH[3][4];
#pragma unroll
    for (int p = 0; p < 3; ++p)
#pragma unroll
        for (int kt = 0; kt < 4; ++kt) {
            const size_t roff = (size_t)(g * J3_ + p * 128 + w * 16 + lr) * HG_
                              + kt * 32 + hi * 8;
            aI[p][kt] = cvt_half8(Wih + roff);  pin_frag(aI[p][kt]);
            aH[p][kt] = cvt_half8(Whh + roff);  pin_frag(aH[p][kt]);
        }

    // ---- biases for this lane's 4 j's; fold b_ih+b_hh for r,z gates ----
    const float* bi = bih + g * J3_;
    const float* bh = bhh + g * J3_;
    f32x4 brz0, brz1, bin_, bhn_;
    {
        const f32x4 i0 = *(const f32x4*)(bi + jl);
        const f32x4 h0 = *(const f32x4*)(bh + jl);
        const f32x4 i1 = *(const f32x4*)(bi + 128 + jl);
        const f32x4 h1 = *(const f32x4*)(bh + 128 + jl);
        brz0 = i0 + h0; brz1 = i1 + h1;
        bin_ = *(const f32x4*)(bi + 256 + jl);
        bhn_ = *(const f32x4*)(bh + 256 + jl);
    }

    // ---- h = 0 init (each lane writes its own swizzled slot in buf 0) ----
    f32x4 hreg = (f32x4){0.f, 0.f, 0.f, 0.f};
    {
        const int gi = (2 * w + (hi >> 1)) ^ (lr & 7);
        half4 z4 = (half4){(_Float16)0.f, (_Float16)0.f, (_Float16)0.f, (_Float16)0.f};
        *(half4*)&hmem[0][lr * 128 + gi * 8 + (hi & 1) * 4] = z4;
    }
    __syncthreads();   // one full barrier outside the loop is fine

    const _Float16* xrow = x16 + (size_t)b * T_ * IN_ + g * HG_;   // + tau*IN_
    float*          orow = out + (size_t)b * T_ * IN_ + g * HG_;   // + tau*IN_

    // ---- prologue: prefetch x frags for tau = 0, 1 ----
    half8 bxA[4], bxB[4];
#pragma unroll
    for (int kt = 0; kt < 4; ++kt) bxA[kt] = *(const half8*)(xrow + kt * 32 + hi * 8);
#pragma unroll
    for (int kt = 0; kt < 4; ++kt) bxB[kt] = *(const half8*)(xrow + IN_ + kt * 32 + hi * 8);

#define GRU_STEP(TAU, BX)                                                          \
    do {                                                                           \
        /* x-projection (h-independent; BX arrived >=1 step ago) */                \
        f32x4 xa0 = (f32x4){0.f,0.f,0.f,0.f}, xa1 = xa0, xa2 = xa0;                \
        _Pragma("unroll")                                                          \
        for (int kt = 0; kt < 4; ++kt) {                                           \
            xa0 = __builtin_amdgcn_mfma_f32_16x16x32_f16(aI[0][kt], BX[kt], xa0, 0, 0, 0); \
            xa1 = __builtin_amdgcn_mfma_f32_16x16x32_f16(aI[1][kt], BX[kt], xa1, 0, 0, 0); \
            xa2 = __builtin_amdgcn_mfma_f32_16x16x32_f16(aI[2][kt], BX[kt], xa2, 0, 0, 0); \
        }                                                                          \
        /* reload BX for TAU+2 (2 full steps of latency budget; stays in */        \
        /* flight across the lds-only barriers below) */                           \
        {                                                                          \
            int tn = (TAU) + 2; if (tn > T_ - 1) tn = T_ - 1;                      \
            const _Float16* px = xrow + (size_t)tn * IN_;                          \
            _Pragma("unroll")                                                      \
            for (int kt = 0; kt < 4; ++kt)                                         \
                BX[kt] = *(const half8*)(px + kt * 32 + hi * 8);                   \
        }                                                                          \
        /* h-projection from swizzled LDS */                                       \
        const int pb = (TAU) & 1;                                                  \
        f32x4 ha0 = (f32x4){0.f,0.f,0.f,0.f}, ha1 = ha0, ha2 = ha0;                \
        _Pragma("unroll")                                                          \
        for (int kt = 0; kt < 4; ++kt) {                                           \
            const half8 bf = *(const half8*)&hmem[pb][lr * 128 + ((4 * kt + hi) ^ (lr & 7)) * 8]; \
            ha0 = __builtin_amdgcn_mfma_f32_16x16x32_f16(aH[0][kt], bf, ha0, 0, 0, 0); \
            ha1 = __builtin_amdgcn_mfma_f32_16x16x32_f16(aH[1][kt], bf, ha1, 0, 0, 0); \
            ha2 = __builtin_amdgcn_mfma_f32_16x16x32_f16(aH[2][kt], bf, ha2, 0, 0, 0); \
        }                                                                          \
        /* lane-local gates (seq = lr, 4 j's), all fp32 */                         \
        f32x4 hnew;                                                                \
        _Pragma("unroll")                                                          \
        for (int r = 0; r < 4; ++r) {                                              \
            const float ar  = xa0[r] + ha0[r] + brz0[r];                           \
            const float az  = xa1[r] + ha1[r] + brz1[r];                           \
            const float xnv = xa2[r] + bin_[r];                                    \
            const float hnv = ha2[r] + bhn_[r];                                    \
            const float rg = __builtin_amdgcn_rcpf(1.f + __builtin_amdgcn_exp2f(-1.4426950f * ar)); \
            const float zg = __builtin_amdgcn_rcpf(1.f + __builtin_amdgcn_exp2f(-1.4426950f * az)); \
            const float pre = xnv + rg * hnv;                                      \
            const float th  = 2.f * __builtin_amdgcn_rcpf(1.f + __builtin_amdgcn_exp2f(-2.8853900f * pre)) - 1.f; \
            hnew[r] = th + zg * (hreg[r] - th);                                    \
        }                                                                          \
        hreg = hnew;                                                               \
        /* write h for next step (swizzled) + output store */                      \
        {                                                                          \
            half4 hh;                                                              \
            _Pragma("unroll")                                                      \
            for (int r = 0; r < 4; ++r) hh[r] = (_Float16)hnew[r];                 \
            const int gi = (2 * w + (hi >> 1)) ^ (lr & 7);                         \
            *(half4*)&hmem[pb ^ 1][lr * 128 + gi * 8 + (hi & 1) * 4] = hh;         \
            *(f32x4*)(orow + (size_t)(TAU) * IN_ + jl) = hnew;                     \
        }                                                                          \
        barrier_lds_only();   /* lgkmcnt(0)+s_barrier; vmcnt NOT drained */        \
    } while (0)

    for (int t = 0; t < T_; t += 2) {
        GRU_STEP(t,     bxA);
        GRU_STEP(t + 1, bxB);
    }
#undef GRU_STEP
}

// ---------------------------------------------------------------------------
extern "C" void kernel_launch(void* const* d_in, const int* in_sizes, int n_in,
                              void* d_out, int out_size, void* d_ws, size_t ws_size,
                              hipStream_t stream) {
    (void)in_sizes; (void)n_in; (void)out_size; (void)ws_size;
    const float* x   = (const float*)d_in[0];
    const float* Wih = (const float*)d_in[1];
    const float* Whh = (const float*)d_in[2];
    const float* bih = (const float*)d_in[3];
    const float* bhh = (const float*)d_in[4];
    float* out = (float*)d_out;

    _Float16* x16 = (_Float16*)d_ws;    // 64*500*1024*2 = 65.5 MB

    cvt_x<<<4096, 256, 0, stream>>>(x, x16);
    gru_fused<<<32, 512, 0, stream>>>(Wih, Whh, bih, bhh, x16, out);
}

// Round 8
// 550.825 us; speedup vs baseline: 1.3710x; 1.0110x over previous
//
#include <hip/hip_runtime.h>
#include <math.h>

#define B_   64
#define T_   500
#define IN_  1024
#define G_   8
#define HG_  128
#define J3_  384   // 3*HG

typedef _Float16 half8 __attribute__((ext_vector_type(8)));
typedef _Float16 half4 __attribute__((ext_vector_type(4)));
typedef float    f32x4 __attribute__((ext_vector_type(4)));

static __device__ __forceinline__ half8 cvt_half8(const float* p) {
    const float4 a = *(const float4*)p;
    const float4 b = *(const float4*)(p + 4);
    half8 h;
    h[0] = (_Float16)a.x; h[1] = (_Float16)a.y; h[2] = (_Float16)a.z; h[3] = (_Float16)a.w;
    h[4] = (_Float16)b.x; h[5] = (_Float16)b.y; h[6] = (_Float16)b.z; h[7] = (_Float16)b.w;
    return h;
}

// opaque reg-to-reg barrier: prevents rematerialization of W fragments
static __device__ __forceinline__ void pin_frag(half8& h) {
    f32x4 t = __builtin_bit_cast(f32x4, h);
    float a = t[0], b = t[1], c = t[2], d = t[3];
    asm volatile("" : "+v"(a), "+v"(b), "+v"(c), "+v"(d));
    t[0] = a; t[1] = b; t[2] = c; t[3] = d;
    h = __builtin_bit_cast(half8, t);
}

// LDS-only barrier: orders ds ops across the workgroup WITHOUT draining vmcnt
// (x prefetch loads and out stores stay in flight across steps).
static __device__ __forceinline__ void barrier_lds_only() {
    asm volatile("s_waitcnt lgkmcnt(0)\n\ts_barrier" ::: "memory");
}

// ---------------------------------------------------------------------------
// Kernel 0: cast x (fp32) -> x16 (f16), one-shot, memory-bound (~15 us).
// ---------------------------------------------------------------------------
__global__ __launch_bounds__(256)
void cvt_x(const float* __restrict__ x, _Float16* __restrict__ x16)
{
    const size_t n4 = (size_t)B_ * T_ * IN_ / 4;
    const size_t stride = (size_t)gridDim.x * 256;
    for (size_t i = (size_t)blockIdx.x * 256 + threadIdx.x; i < n4; i += stride) {
        const float4 v = ((const float4*)x)[i];
        half4 h;
        h[0] = (_Float16)v.x; h[1] = (_Float16)v.y;
        h[2] = (_Float16)v.z; h[3] = (_Float16)v.w;
        ((half4*)x16)[i] = h;
    }
}

// ---------------------------------------------------------------------------
// Kernel 1 (structure G2): fused GRU, latency-shaved step.
// 32 blocks x 512 thr; 16 sequences per block (MFMA col = seq = lr).
// Step layout (critical-path-aware):
//   [ds_read h issue] [out-store(t-1)] [x-MFMA(t+1), bias-seeded]
//   [BX(t+2) reload]  [h-MFMA(t), 2+2 split chains] [gates(t), lane-local]
//   [h write swizzled] [lgkmcnt(0)+s_barrier] [out-store deferred]
// Biases ride in MFMA C-in (free). xa carried across the barrier in regs.
// ---------------------------------------------------------------------------
__global__ __launch_bounds__(512, 1)
void gru_fused(const float* __restrict__ Wih, const float* __restrict__ Whh,
               const float* __restrict__ bih, const float* __restrict__ bhh,
               const _Float16* __restrict__ x16, float* __restrict__ out)
{
    const int tid  = threadIdx.x;
    const int lane = tid & 63;
    const int w    = tid >> 6;        // wave 0..7 == j-tile
    const int lr   = lane & 15;       // seq within block / MFMA col
    const int hi   = lane >> 4;       // 0..3
    const int blk  = blockIdx.x;      // 0..31
    const int g    = blk & 7;
    const int bq   = blk >> 3;        // 0..3
    const int b    = bq * 16 + lr;    // this lane's sequence
    const int jl   = w * 16 + hi * 4; // this lane's j base (4 consecutive)

    __shared__ _Float16 hmem[2][16 * 128];   // [buf][swizzled seq-major], 8 KB

    // ---- persistent pinned fragments: rows p*128 + 16w + lr, k = kt*32+hi*8 ----
    half8 aI[3][4], aH[3][4];
#pragma unroll
    for (int p = 0; p < 3; ++p)
#pragma unroll
        for (int kt = 0; kt < 4; ++kt) {
            const size_t roff = (size_t)(g * J3_ + p * 128 + w * 16 + lr) * HG_
                              + kt * 32 + hi * 8;
            aI[p][kt] = cvt_half8(Wih + roff);  pin_frag(aI[p][kt]);
            aH[p][kt] = cvt_half8(Whh + roff);  pin_frag(aH[p][kt]);
        }

    // ---- biases for this lane's 4 j's; r,z: bih+bhh fused into x-chain seed;
    //      n: bih seeds x-chain, bhh seeds h-chain (they must stay separate) ----
    const float* bi = bih + g * J3_;
    const float* bh = bhh + g * J3_;
    f32x4 brz0, brz1, bin_, bhn_;
    {
        const f32x4 i0 = *(const f32x4*)(bi + jl);
        const f32x4 h0 = *(const f32x4*)(bh + jl);
        const f32x4 i1 = *(const f32x4*)(bi + 128 + jl);
        const f32x4 h1 = *(const f32x4*)(bh + 128 + jl);
        brz0 = i0 + h0; brz1 = i1 + h1;
        bin_ = *(const f32x4*)(bi + 256 + jl);
        bhn_ = *(const f32x4*)(bh + 256 + jl);
    }

    // ---- h = 0 init (each lane writes its own swizzled slot in buf 0) ----
    f32x4 hreg = (f32x4){0.f, 0.f, 0.f, 0.f};
    {
        const int gi = (2 * w + (hi >> 1)) ^ (lr & 7);
        half4 z4 = (half4){(_Float16)0.f, (_Float16)0.f, (_Float16)0.f, (_Float16)0.f};
        *(half4*)&hmem[0][lr * 128 + gi * 8 + (hi & 1) * 4] = z4;
    }

    const _Float16* xrow = x16 + (size_t)b * T_ * IN_ + g * HG_;   // + tau*IN_
    float*          orow = out + (size_t)b * T_ * IN_ + g * HG_;   // + tau*IN_

    // ---- prologue: bxB <- x(0), bxA <- x(1); xaA = xproj(x(0)) ----
    half8 bxA[4], bxB[4];
#pragma unroll
    for (int kt = 0; kt < 4; ++kt) bxB[kt] = *(const half8*)(xrow + kt * 32 + hi * 8);
#pragma unroll
    for (int kt = 0; kt < 4; ++kt) bxA[kt] = *(const half8*)(xrow + IN_ + kt * 32 + hi * 8);

    f32x4 xaA0 = brz0, xaA1 = brz1, xaA2 = bin_;
#pragma unroll
    for (int kt = 0; kt < 4; ++kt) {
        xaA0 = __builtin_amdgcn_mfma_f32_16x16x32_f16(aI[0][kt], bxB[kt], xaA0, 0, 0, 0);
        xaA1 = __builtin_amdgcn_mfma_f32_16x16x32_f16(aI[1][kt], bxB[kt], xaA1, 0, 0, 0);
        xaA2 = __builtin_amdgcn_mfma_f32_16x16x32_f16(aI[2][kt], bxB[kt], xaA2, 0, 0, 0);
    }
    f32x4 xaB0, xaB1, xaB2;

    __syncthreads();   // full barrier once, outside the loop

    // NOTE on x16 over-read: steps t=498,499 prefetch/project x(500),x(501)
    // (results unused). That reads <=4KB past the 65.5MB x16 region, still
    // inside d_ws (ws >= 197MB per earlier rounds). Safe garbage.

#define GRU_STEP(TAU, BXc, BXn, xc0, xc1, xc2, xn0, xn1, xn2)                      \
    do {                                                                           \
        const int pb = (TAU) & 1;                                                  \
        /* 1. h B-frags: issue ds_reads first (latency hidden by 2&3) */           \
        const half8 bf0 = *(const half8*)&hmem[pb][lr * 128 + (( 0 + hi) ^ (lr & 7)) * 8]; \
        const half8 bf1 = *(const half8*)&hmem[pb][lr * 128 + (( 4 + hi) ^ (lr & 7)) * 8]; \
        const half8 bf2 = *(const half8*)&hmem[pb][lr * 128 + (( 8 + hi) ^ (lr & 7)) * 8]; \
        const half8 bf3 = *(const half8*)&hmem[pb][lr * 128 + ((12 + hi) ^ (lr & 7)) * 8]; \
        /* 2. x-projection for TAU+1 (bias-seeded; h-independent filler) */        \
        xn0 = brz0; xn1 = brz1; xn2 = bin_;                                        \
        _Pragma("unroll")                                                          \
        for (int kt = 0; kt < 4; ++kt) {                                           \
            xn0 = __builtin_amdgcn_mfma_f32_16x16x32_f16(aI[0][kt], BXc[kt], xn0, 0, 0, 0); \
            xn1 = __builtin_amdgcn_mfma_f32_16x16x32_f16(aI[1][kt], BXc[kt], xn1, 0, 0, 0); \
            xn2 = __builtin_amdgcn_mfma_f32_16x16x32_f16(aI[2][kt], BXc[kt], xn2, 0, 0, 0); \
        }                                                                          \
        /* 3. reload BXn <- x(TAU+2); stays in flight across barriers */           \
        {                                                                          \
            const _Float16* px = xrow + (size_t)((TAU) + 2) * IN_;                 \
            _Pragma("unroll")                                                      \
            for (int kt = 0; kt < 4; ++kt)                                         \
                BXn[kt] = *(const half8*)(px + kt * 32 + hi * 8);                  \
        }                                                                          \
        /* 4. h-MFMA, split 2+2 chains per gate (shorter dep path) */              \
        f32x4 h0a = (f32x4){0.f,0.f,0.f,0.f}, h0b = h0a;                           \
        f32x4 h1a = h0a, h1b = h0a, h2b = h0a;                                     \
        f32x4 h2a = bhn_;                                                          \
        h0a = __builtin_amdgcn_mfma_f32_16x16x32_f16(aH[0][0], bf0, h0a, 0, 0, 0); \
        h1a = __builtin_amdgcn_mfma_f32_16x16x32_f16(aH[1][0], bf0, h1a, 0, 0, 0); \
        h2a = __builtin_amdgcn_mfma_f32_16x16x32_f16(aH[2][0], bf0, h2a, 0, 0, 0); \
        h0b = __builtin_amdgcn_mfma_f32_16x16x32_f16(aH[0][2], bf2, h0b, 0, 0, 0); \
        h1b = __builtin_amdgcn_mfma_f32_16x16x32_f16(aH[1][2], bf2, h1b, 0, 0, 0); \
        h2b = __builtin_amdgcn_mfma_f32_16x16x32_f16(aH[2][2], bf2, h2b, 0, 0, 0); \
        h0a = __builtin_amdgcn_mfma_f32_16x16x32_f16(aH[0][1], bf1, h0a, 0, 0, 0); \
        h1a = __builtin_amdgcn_mfma_f32_16x16x32_f16(aH[1][1], bf1, h1a, 0, 0, 0); \
        h2a = __builtin_amdgcn_mfma_f32_16x16x32_f16(aH[2][1], bf1, h2a, 0, 0, 0); \
        h0b = __builtin_amdgcn_mfma_f32_16x16x32_f16(aH[0][3], bf3, h0b, 0, 0, 0); \
        h1b = __builtin_amdgcn_mfma_f32_16x16x32_f16(aH[1][3], bf3, h1b, 0, 0, 0); \
        h2b = __builtin_amdgcn_mfma_f32_16x16x32_f16(aH[2][3], bf3, h2b, 0, 0, 0); \
        const f32x4 ha0 = h0a + h0b;                                               \
        const f32x4 ha1 = h1a + h1b;                                               \
        const f32x4 ha2 = h2a + h2b;                                               \
        /* 5. lane-local gates (seq = lr, 4 j's); biases pre-seeded */             \
        f32x4 hnew;                                                                \
        _Pragma("unroll")                                                          \
        for (int r = 0; r < 4; ++r) {                                              \
            const float ar  = xc0[r] + ha0[r];                                     \
            const float az  = xc1[r] + ha1[r];                                     \
            const float rg = __builtin_amdgcn_rcpf(1.f + __builtin_amdgcn_exp2f(-1.4426950f * ar)); \
            const float zg = __builtin_amdgcn_rcpf(1.f + __builtin_amdgcn_exp2f(-1.4426950f * az)); \
            const float pre = xc2[r] + rg * ha2[r];                                \
            const float th  = 2.f * __builtin_amdgcn_rcpf(1.f + __builtin_amdgcn_exp2f(-2.8853900f * pre)) - 1.f; \
            hnew[r] = th + zg * (hreg[r] - th);                                    \
        }                                                                          \
        hreg = hnew;                                                               \
        /* 6. write h for next step (swizzled), lds-only barrier */                \
        {                                                                          \
            half4 hh;                                                              \
            _Pragma("unroll")                                                      \
            for (int r = 0; r < 4; ++r) hh[r] = (_Float16)hnew[r];                 \
            const int gi = (2 * w + (hi >> 1)) ^ (lr & 7);                         \
            *(half4*)&hmem[pb ^ 1][lr * 128 + gi * 8 + (hi & 1) * 4] = hh;         \
        }                                                                          \
        barrier_lds_only();                                                        \
        /* 7. out store AFTER barrier: lands in next step's ds-wait window */      \
        *(f32x4*)(orow + (size_t)(TAU) * IN_ + jl) = hnew;                         \
    } while (0)

    for (int t = 0; t < T_; t += 2) {
        GRU_STEP(t,     bxA, bxB, xaA0, xaA1, xaA2, xaB0, xaB1, xaB2);
        GRU_STEP(t + 1, bxB, bxA, xaB0, xaB1, xaB2, xaA0, xaA1, xaA2);
    }
#undef GRU_STEP
}

// ---------------------------------------------------------------------------
extern "C" void kernel_launch(void* const* d_in, const int* in_sizes, int n_in,
                              void* d_out, int out_size, void* d_ws, size_t ws_size,
                              hipStream_t stream) {
    (void)in_sizes; (void)n_in; (void)out_size; (void)ws_size;
    const float* x   = (const float*)d_in[0];
    const float* Wih = (const float*)d_in[1];
    const float* Whh = (const float*)d_in[2];
    const float* bih = (const float*)d_in[3];
    const float* bhh = (const float*)d_in[4];
    float* out = (float*)d_out;

    _Float16* x16 = (_Float16*)d_ws;    // 65.5 MB (+<=4KB over-read slack)

    cvt_x<<<4096, 256, 0, stream>>>(x, x16);
    gru_fused<<<32, 512, 0, stream>>>(Wih, Whh, bih, bhh, x16, out);
}